// Round 1
// 619.981 us; speedup vs baseline: 1.0402x; 1.0402x over previous
//
#include <hip/hip_runtime.h>
#include <stdint.h>

#define Bn  256
#define Hn  512
#define En  512
#define Vn  32000
#define Fn  512
#define HWn 256

typedef unsigned short u16;
typedef unsigned int u32;
typedef __attribute__((ext_vector_type(4))) float f32x4;
typedef __attribute__((ext_vector_type(8))) short bf16x8;

__device__ __forceinline__ u16 hi16(float x) {
    return (u16)((__float_as_uint(x) + 0x8000u) >> 16);
}
__device__ __forceinline__ u32 pack2(float a, float b) {
    return ((__float_as_uint(a) + 0x8000u) >> 16) |
           ((__float_as_uint(b) + 0x8000u) & 0xffff0000u);
}
__device__ __forceinline__ float sigm(float x) { return 1.0f / (1.0f + __expf(-x)); }
__device__ __forceinline__ float tanh_fast(float x) {
    x = fminf(15.f, fmaxf(-15.f, x));
    float e = __expf(2.f * x);
    return 1.f - 2.f / (e + 1.f);
}

#define GLDS16(g, l) __builtin_amdgcn_global_load_lds( \
    (const __attribute__((address_space(1))) void*)(g), \
    (__attribute__((address_space(3))) void*)(l), 16, 0, 0)

// ---------------------------------------------------------------------------
// Generic MFMA GEMM: out[m, n] = sum_seg A_s[m,:512] . W_s[n, koff:koff+512] + biases
// M = 256 (4 btiles x 64), N tiles of 32 (blockIdx.y). 512 thr = 8 waves,
// wave w: m-tile = w&3 (16 rows), n-tile = w>>2 (16 cols). K chunks of 128.
// LDS rows padded to 136 elems (272 B = 17*16: b128-aligned, bank stride 4).
__global__ __launch_bounds__(512) void k_gemm(
    const float* __restrict__ A0, const float* __restrict__ A1, const float* __restrict__ A2,
    const float* __restrict__ W0, const float* __restrict__ W1, const float* __restrict__ W2,
    int ws0, int ws1, int ws2, int ko0, int ko1, int ko2, int nseg,
    const float* __restrict__ bias1, const float* __restrict__ bias2,
    float* __restrict__ out, int ostride)
{
    __shared__ u16 Al[64 * 136];
    __shared__ u16 Wl[32 * 136];
    int tid = threadIdx.x;
    int b0 = blockIdx.x * 64, n0 = blockIdx.y * 32;
    int w = tid >> 6, lane = tid & 63, lm = lane & 15, quad = lane >> 4;
    int ti = w & 3, nt = w >> 2;
    const float* As[3] = {A0, A1, A2};
    const float* Ws[3] = {W0, W1, W2};
    int wss[3] = {ws0, ws1, ws2};
    int kos[3] = {ko0, ko1, ko2};
    f32x4 ae = {0.f, 0.f, 0.f, 0.f}, ao = {0.f, 0.f, 0.f, 0.f};
    int ra = ti * 16 + lm, rw = nt * 16 + lm;
    for (int s = 0; s < nseg; s++) {
        const float* Ap = As[s];
        const float* Wp = Ws[s];
        int wstr = wss[s], koff = kos[s];
        for (int kc = 0; kc < 4; kc++) {
            __syncthreads();
            #pragma unroll
            for (int i = 0; i < 4; i++) {          // A: 64 rows x 128 k
                int idx4 = i * 512 + tid;
                int k4 = (idx4 & 31) * 4;
                int row = idx4 >> 5;
                float4 v = *(const float4*)(Ap + (b0 + row) * 512 + kc * 128 + k4);
                u32 lo = pack2(v.x, v.y), hi = pack2(v.z, v.w);
                *(uint2*)&Al[row * 136 + k4] = make_uint2(lo, hi);
            }
            #pragma unroll
            for (int i = 0; i < 2; i++) {          // W: 32 rows x 128 k
                int idx4 = i * 512 + tid;
                int k4 = (idx4 & 31) * 4;
                int row = idx4 >> 5;
                float4 v = *(const float4*)(Wp + (size_t)(n0 + row) * wstr + koff + kc * 128 + k4);
                u32 lo = pack2(v.x, v.y), hi = pack2(v.z, v.w);
                *(uint2*)&Wl[row * 136 + k4] = make_uint2(lo, hi);
            }
            __syncthreads();
            #pragma unroll
            for (int ks = 0; ks < 4; ks += 2) {
                bf16x8 a0 = *(const bf16x8*)&Al[ra * 136 + ks * 32 + quad * 8];
                bf16x8 w0 = *(const bf16x8*)&Wl[rw * 136 + ks * 32 + quad * 8];
                ae = __builtin_amdgcn_mfma_f32_16x16x32_bf16(a0, w0, ae, 0, 0, 0);
                bf16x8 a1 = *(const bf16x8*)&Al[ra * 136 + (ks + 1) * 32 + quad * 8];
                bf16x8 w1 = *(const bf16x8*)&Wl[rw * 136 + (ks + 1) * 32 + quad * 8];
                ao = __builtin_amdgcn_mfma_f32_16x16x32_bf16(a1, w1, ao, 0, 0, 0);
            }
        }
    }
    int n = n0 + nt * 16 + lm;
    float bias = bias1[n] + (bias2 ? bias2[n] : 0.f);
    #pragma unroll
    for (int r = 0; r < 4; r++) {
        int m = b0 + ti * 16 + quad * 4 + r;       // D: col=lane&15, row=quad*4+reg
        out[(size_t)m * ostride + n] = ae[r] + ao[r] + bias;
    }
}

// ---------------------------------------------------------------------------
// Prep: WFw [512 h][512 f] fp32 -> Wz bf16, rows of 1024 B, pre-swizzled:
// byte-within-row ^= ((h&7)<<4). Enables linear global_load_lds staging with
// conflict-free swizzled ds_read_b128 in k_scores.
__global__ __launch_bounds__(256) void k_prep_w(const float* __restrict__ W,
                                                u16* __restrict__ Wz) {
    int idx = blockIdx.x * 256 + threadIdx.x;      // 512 rows * 64 chunks
    int h = idx >> 6, c = idx & 63;
    const float* src = W + h * 512 + c * 8;
    float4 v0 = *(const float4*)(src);
    float4 v1 = *(const float4*)(src + 4);
    u32 p0 = pack2(v0.x, v0.y), p1 = pack2(v0.z, v0.w);
    u32 p2 = pack2(v1.x, v1.y), p3 = pack2(v1.z, v1.w);
    int byte = (c * 16) ^ ((h & 7) << 4);
    *(uint4*)((char*)Wz + (size_t)h * 1024 + byte) = make_uint4(p0, p1, p2, p3);
}

// ---------------------------------------------------------------------------
// K2 (MFMA): sc[b,i] = (1/51.2) * sum_h tanh(ht[b,h] + sum_f flat[b,f,i]*WFw[h,f])
// Block (b, it): i-tile 128, 256 thr = 4 waves in 2x2, each wave owns a 64x64
// output tile -> 16 MFMA per 8 fragment reads (R=0.5). K chunked by 128.
// W staged via global_load_lds from pre-swizzled Wz (zero VALU staging).
// A transposed-staged from fp32 flat into a byte-rotation layout that makes
// BOTH the scalar b16 transpose-writes and the b32x4 fragment reads ~2-way.
//
// A layout: element (il,kk) at byte il*256 + ((2*kk) ^ sx(il)), where sx mixes
// il bits {0^3,1^6,4,5,2} into byte bits {2,3,4,5,6}. Verified spread:
//   frag reads (lanes vary lm0..3, q): 32 banks x2   -> free
//   stage writes (lanes vary il bits 2..6): 32 banks x2 -> free
__device__ __forceinline__ int sxof(int il) {
    return (((il ^ (il >> 3)) & 1) << 2) |
           ((((il >> 1) ^ (il >> 6)) & 1) << 3) |
           (((il >> 4) & 1) << 4) |
           (((il >> 5) & 1) << 5) |
           (((il >> 2) & 1) << 6);
}
__device__ __forceinline__ int aidx(int il, int kk) {   // u16 index into Al
    return il * 128 + (((kk * 2) ^ sxof(il)) >> 1);
}

__global__ __launch_bounds__(256) void k_scores(const float* __restrict__ flat,
                                                const u16* __restrict__ Wz,
                                                const float* __restrict__ ht,
                                                float* __restrict__ sc) {
    __shared__ u16 Al[128 * 128];   // A chunk [il][kk], rotated, 32 KB
    __shared__ u16 Wl[128 * 128];   // W chunk [hl][kk], XOR-swizzled, 32 KB
    int b = blockIdx.x, it = blockIdx.y, tid = threadIdx.x;
    int i0 = it * 128;
    int w = tid >> 6, lane = tid & 63, lm = lane & 15, quad = lane >> 4;
    int wi = w & 1, wh = w >> 1;
    const float* fb = flat + (size_t)b * (Fn * HWn) + i0;
    float part[4][4] = {{0.f}};
    f32x4 zero = {0.f, 0.f, 0.f, 0.f};

    for (int hp = 0; hp < 4; hp++) {               // h-pass of 128
        f32x4 acc[4][4];
        #pragma unroll
        for (int m = 0; m < 4; m++)
            #pragma unroll
            for (int n = 0; n < 4; n++) acc[m][n] = zero;

        for (int kc = 0; kc < 4; kc++) {           // K chunk of 128
            __syncthreads();
            // --- W chunk DMA: rows hp*128 + [w*32, w*32+32), 256 B per row
            {
                const char* wsrc = (const char*)Wz +
                    (size_t)(hp * 128 + w * 32) * 1024 + kc * 256;
                #pragma unroll
                for (int j = 0; j < 8; j++) {
                    const char* src = wsrc + (size_t)(j * 4 + (lane >> 4)) * 1024
                                    + (lane & 15) * 16;
                    GLDS16(src, &Wl[(w * 32 + j * 4) * 128]);
                }
            }
            // --- A chunk transpose-stage: Al[il][kk] = bf16(flat[b, kc*128+kk, i0+il])
            #pragma unroll 4
            for (int t = 0; t < 16; t++) {
                int idx = t * 256 + tid;
                int il4 = (idx & 31) * 4;
                int kk = idx >> 5;
                float4 v = *(const float4*)(fb + (size_t)(kc * 128 + kk) * HWn + il4);
                Al[aidx(il4 + 0, kk)] = hi16(v.x);
                Al[aidx(il4 + 1, kk)] = hi16(v.y);
                Al[aidx(il4 + 2, kk)] = hi16(v.z);
                Al[aidx(il4 + 3, kk)] = hi16(v.w);
            }
            __syncthreads();
            // --- compute: wave (wi, wh) owns rows wi*64.. and cols wh*64..
            #pragma unroll
            for (int ks = 0; ks < 4; ks++) {
                bf16x8 af[4], wf[4];
                #pragma unroll
                for (int m = 0; m < 4; m++) {
                    int il = wi * 64 + m * 16 + lm;
                    union { u32 u[4]; bf16x8 v; } cu;
                    #pragma unroll
                    for (int j = 0; j < 4; j++)
                        cu.u[j] = *(const u32*)&Al[aidx(il, ks * 32 + quad * 8 + 2 * j)];
                    af[m] = cu.v;
                }
                #pragma unroll
                for (int n = 0; n < 4; n++) {
                    int row = wh * 64 + n * 16 + lm;
                    wf[n] = *(const bf16x8*)&Wl[row * 128 +
                             ((ks * 32 + quad * 8) ^ ((row & 7) << 3))];
                }
                #pragma unroll
                for (int m = 0; m < 4; m++)
                    #pragma unroll
                    for (int n = 0; n < 4; n++)
                        acc[m][n] = __builtin_amdgcn_mfma_f32_16x16x32_bf16(
                            af[m], wf[n], acc[m][n], 0, 0, 0);
            }
        }
        // tanh + h-partial: D layout col=lane&15 (h), row=quad*4+reg (i)
        #pragma unroll
        for (int n = 0; n < 4; n++) {
            float hb = ht[b * Hn + hp * 128 + wh * 64 + n * 16 + lm];
            #pragma unroll
            for (int m = 0; m < 4; m++)
                #pragma unroll
                for (int r = 0; r < 4; r++)
                    part[m][r] += tanh_fast(hb + acc[m][n][r]);
        }
    }
    // reduce over lm (h-lanes), combine waves in LDS, write sc directly
    __syncthreads();
    float* scf = (float*)Al;
    if (tid < 128) scf[tid] = 0.f;
    __syncthreads();
    #pragma unroll
    for (int m = 0; m < 4; m++)
        #pragma unroll
        for (int r = 0; r < 4; r++) {
            float p = part[m][r];
            p += __shfl_xor(p, 1); p += __shfl_xor(p, 2);
            p += __shfl_xor(p, 4); p += __shfl_xor(p, 8);
            if (lm == 0) atomicAdd(&scf[wi * 64 + m * 16 + quad * 4 + r], p);
        }
    __syncthreads();
    if (tid < 128) sc[b * HWn + i0 + tid] = scf[tid] * (1.0f / 51.2f);
}

// ---------------------------------------------------------------------------
// K3: attn = softmax_i(sc[b,:]); ctx[b,f] = sum_i attn[i]*flat[b,f,i]
// ctx phase: wave per f-row stripe, float4 coalesced + shuffle reduce.
__global__ void k_attn_ctx(const float* __restrict__ sc, const float* __restrict__ flat,
                           float* __restrict__ ctx) {
    __shared__ float sa[HWn], r1[HWn];
    int b = blockIdx.x, tid = threadIdx.x;
    float x = sc[b * HWn + tid];
    r1[tid] = x; __syncthreads();
    for (int off = 128; off; off >>= 1) {
        if (tid < off) r1[tid] = fmaxf(r1[tid], r1[tid + off]);
        __syncthreads();
    }
    float M = r1[0];
    __syncthreads();
    float e = __expf(x - M);
    r1[tid] = e; __syncthreads();
    for (int off = 128; off; off >>= 1) {
        if (tid < off) r1[tid] += r1[tid + off];
        __syncthreads();
    }
    sa[tid] = e / r1[0];
    __syncthreads();
    int w = tid >> 6, lane = tid & 63;
    const float4* f4 = (const float4*)(flat + (size_t)b * (Fn * HWn));
    const float4* s4 = (const float4*)sa;
    float4 sv = s4[lane];
    for (int f = w; f < Fn; f += 4) {
        float4 v = f4[f * 64 + lane];
        float acc = v.x * sv.x + v.y * sv.y + v.z * sv.z + v.w * sv.w;
        acc += __shfl_xor(acc, 32); acc += __shfl_xor(acc, 16);
        acc += __shfl_xor(acc, 8);  acc += __shfl_xor(acc, 4);
        acc += __shfl_xor(acc, 2);  acc += __shfl_xor(acc, 1);
        if (lane == 0) ctx[b * Fn + f] = acc;
    }
}

// ---------------------------------------------------------------------------
// K5: LSTM cell elementwise
__global__ void k_lstm(const float* __restrict__ gates, const float* __restrict__ cell,
                       float* __restrict__ oh, float* __restrict__ oc) {
    int idx = blockIdx.x * 256 + threadIdx.x;
    int b = idx >> 9, h = idx & 511;
    const float* g = gates + b * 2048;
    float gi = g[h], gf = g[512 + h], gg = g[1024 + h], go = g[1536 + h];
    float c = cell[idx];
    float cn = sigm(gf) * c + sigm(gi) * tanhf(gg);
    float hv = sigm(go) * tanhf(cn);
    oh[idx] = hv;
    oc[idx] = cn;
}

// ---------------------------------------------------------------------------
// K7: row softmax over V
__global__ void k_vsoftmax(const float* __restrict__ logits, float* __restrict__ probs) {
    __shared__ float rm[256], rs[256];
    int b = blockIdx.x, tid = threadIdx.x;
    const float* row = logits + (size_t)b * Vn;
    float m = -1e30f, s = 0.f;
    for (int v = tid; v < Vn; v += 256) {
        float x = row[v];
        if (x > m) { s = s * __expf(m - x); m = x; }
        s += __expf(x - m);
    }
    rm[tid] = m; rs[tid] = s; __syncthreads();
    for (int off = 128; off; off >>= 1) {
        if (tid < off) {
            float m2 = rm[tid + off], s2 = rs[tid + off];
            float M = fmaxf(rm[tid], m2);
            rs[tid] = rs[tid] * __expf(rm[tid] - M) + s2 * __expf(m2 - M);
            rm[tid] = M;
        }
        __syncthreads();
    }
    float M = rm[0], S = rs[0];
    float* prow = probs + (size_t)b * Vn;
    for (int v = tid; v < Vn; v += 256) prow[v] = __expf(row[v] - M) / S;
}

// ---------------------------------------------------------------------------
extern "C" void kernel_launch(void* const* d_in, const int* in_sizes, int n_in,
                              void* d_out, int out_size, void* d_ws, size_t ws_size,
                              hipStream_t stream) {
    const float* tok    = (const float*)d_in[0];
    const float* hidden = (const float*)d_in[1];
    const float* cell   = (const float*)d_in[2];
    const float* img    = (const float*)d_in[3];
    const float* Whw    = (const float*)d_in[4];
    const float* Whb    = (const float*)d_in[5];
    const float* WFw    = (const float*)d_in[6];
    const float* WFb    = (const float*)d_in[7];
    const float* Wih    = (const float*)d_in[8];
    const float* bih    = (const float*)d_in[9];
    const float* Whh    = (const float*)d_in[10];
    const float* bhh    = (const float*)d_in[11];
    const float* Wow    = (const float*)d_in[12];
    const float* Wob    = (const float*)d_in[13];

    float* out = (float*)d_out;
    float* out_probs  = out;                              // [B*V]
    float* out_h      = out + (size_t)Bn * Vn;            // [B*H]
    float* out_c      = out_h + (size_t)Bn * Hn;          // [B*H]
    float* out_logits = out_c + (size_t)Bn * Hn;          // [B*V]

    float* ws    = (float*)d_ws;
    float* ht    = ws;                // 131072 floats
    float* sc    = ht + 131072;       // 65536
    float* ctx   = sc + 65536;        // 131072
    float* gates = ctx + 131072;      // 524288
    u16*   Wz    = (u16*)(gates + 524288);   // 262144 u16 = 512 KB (~3.9 MB total)

    // pre-swizzled bf16 WFw for k_scores DMA staging (no deps, run first)
    k_prep_w<<<dim3(128), 256, 0, stream>>>(WFw, Wz);

    // ht = hidden @ Whw^T + Whb + WFb
    k_gemm<<<dim3(4, 16), 512, 0, stream>>>(
        hidden, nullptr, nullptr, Whw, nullptr, nullptr,
        512, 0, 0, 0, 0, 0, 1, Whb, WFb, ht, 512);

    k_scores<<<dim3(256, 2), 256, 0, stream>>>(img, Wz, ht, sc);
    k_attn_ctx<<<dim3(256), 256, 0, stream>>>(sc, img, ctx);

    // gates = [tok|ctx] @ Wih^T + hid @ Whh^T + bih + bhh
    k_gemm<<<dim3(4, 64), 512, 0, stream>>>(
        tok, ctx, hidden, Wih, Wih, Whh,
        1024, 1024, 512, 0, 512, 0, 3, bih, bhh, gates, 2048);

    k_lstm<<<dim3(512), 256, 0, stream>>>(gates, cell, out_h, out_c);

    // logits = h_new @ Wow^T + Wob
    k_gemm<<<dim3(4, 1000), 512, 0, stream>>>(
        out_h, nullptr, nullptr, Wow, nullptr, nullptr,
        512, 0, 0, 0, 0, 0, 1, Wob, nullptr, out_logits, Vn);

    k_vsoftmax<<<dim3(256), 256, 0, stream>>>(out_logits, out_probs);
}

// Round 2
// 512.977 us; speedup vs baseline: 1.2571x; 1.2086x over previous
//
#include <hip/hip_runtime.h>
#include <stdint.h>

#define Bn  256
#define Hn  512
#define En  512
#define Vn  32000
#define Fn  512
#define HWn 256

typedef unsigned short u16;
typedef unsigned int u32;
typedef __attribute__((ext_vector_type(4))) float f32x4;
typedef __attribute__((ext_vector_type(8))) short bf16x8;

__device__ __forceinline__ u16 hi16(float x) {
    return (u16)((__float_as_uint(x) + 0x8000u) >> 16);
}
__device__ __forceinline__ u32 pack2(float a, float b) {
    return ((__float_as_uint(a) + 0x8000u) >> 16) |
           ((__float_as_uint(b) + 0x8000u) & 0xffff0000u);
}
__device__ __forceinline__ float sigm(float x) { return 1.0f / (1.0f + __expf(-x)); }
__device__ __forceinline__ float tanh_fast(float x) {
    x = fminf(15.f, fmaxf(-15.f, x));
    float e = __expf(2.f * x);
    return 1.f - 2.f / (e + 1.f);
}

#define GLDS16(g, l) __builtin_amdgcn_global_load_lds( \
    (const __attribute__((address_space(1))) void*)(g), \
    (__attribute__((address_space(3))) void*)(l), 16, 0, 0)

// ---------------------------------------------------------------------------
// Generic MFMA GEMM (fp32 inputs, VALU bf16 pack). Used for ht + gates (and
// everything in the fallback path). Unchanged from round 1.
__global__ __launch_bounds__(512) void k_gemm(
    const float* __restrict__ A0, const float* __restrict__ A1, const float* __restrict__ A2,
    const float* __restrict__ W0, const float* __restrict__ W1, const float* __restrict__ W2,
    int ws0, int ws1, int ws2, int ko0, int ko1, int ko2, int nseg,
    const float* __restrict__ bias1, const float* __restrict__ bias2,
    float* __restrict__ out, int ostride)
{
    __shared__ u16 Al[64 * 136];
    __shared__ u16 Wl[32 * 136];
    int tid = threadIdx.x;
    int b0 = blockIdx.x * 64, n0 = blockIdx.y * 32;
    int w = tid >> 6, lane = tid & 63, lm = lane & 15, quad = lane >> 4;
    int ti = w & 3, nt = w >> 2;
    const float* As[3] = {A0, A1, A2};
    const float* Ws[3] = {W0, W1, W2};
    int wss[3] = {ws0, ws1, ws2};
    int kos[3] = {ko0, ko1, ko2};
    f32x4 ae = {0.f, 0.f, 0.f, 0.f}, ao = {0.f, 0.f, 0.f, 0.f};
    int ra = ti * 16 + lm, rw = nt * 16 + lm;
    for (int s = 0; s < nseg; s++) {
        const float* Ap = As[s];
        const float* Wp = Ws[s];
        int wstr = wss[s], koff = kos[s];
        for (int kc = 0; kc < 4; kc++) {
            __syncthreads();
            #pragma unroll
            for (int i = 0; i < 4; i++) {
                int idx4 = i * 512 + tid;
                int k4 = (idx4 & 31) * 4;
                int row = idx4 >> 5;
                float4 v = *(const float4*)(Ap + (b0 + row) * 512 + kc * 128 + k4);
                u32 lo = pack2(v.x, v.y), hi = pack2(v.z, v.w);
                *(uint2*)&Al[row * 136 + k4] = make_uint2(lo, hi);
            }
            #pragma unroll
            for (int i = 0; i < 2; i++) {
                int idx4 = i * 512 + tid;
                int k4 = (idx4 & 31) * 4;
                int row = idx4 >> 5;
                float4 v = *(const float4*)(Wp + (size_t)(n0 + row) * wstr + koff + kc * 128 + k4);
                u32 lo = pack2(v.x, v.y), hi = pack2(v.z, v.w);
                *(uint2*)&Wl[row * 136 + k4] = make_uint2(lo, hi);
            }
            __syncthreads();
            #pragma unroll
            for (int ks = 0; ks < 4; ks += 2) {
                bf16x8 a0 = *(const bf16x8*)&Al[ra * 136 + ks * 32 + quad * 8];
                bf16x8 w0 = *(const bf16x8*)&Wl[rw * 136 + ks * 32 + quad * 8];
                ae = __builtin_amdgcn_mfma_f32_16x16x32_bf16(a0, w0, ae, 0, 0, 0);
                bf16x8 a1 = *(const bf16x8*)&Al[ra * 136 + (ks + 1) * 32 + quad * 8];
                bf16x8 w1 = *(const bf16x8*)&Wl[rw * 136 + (ks + 1) * 32 + quad * 8];
                ao = __builtin_amdgcn_mfma_f32_16x16x32_bf16(a1, w1, ao, 0, 0, 0);
            }
        }
    }
    int n = n0 + nt * 16 + lm;
    float bias = bias1[n] + (bias2 ? bias2[n] : 0.f);
    #pragma unroll
    for (int r = 0; r < 4; r++) {
        int m = b0 + ti * 16 + quad * 4 + r;
        out[(size_t)m * ostride + n] = ae[r] + ao[r] + bias;
    }
}

// ---------------------------------------------------------------------------
// Prep: W [rows][512] fp32 -> Wz bf16, rows of 1024 B, pre-swizzled:
// 16B-unit at byte p holds source bytes p ^ ((row&7)<<4). grid = rows/4.
__global__ __launch_bounds__(256) void k_prep_w(const float* __restrict__ W,
                                                u16* __restrict__ Wz) {
    int idx = blockIdx.x * 256 + threadIdx.x;
    int h = idx >> 6, c = idx & 63;
    const float* src = W + (size_t)h * 512 + c * 8;
    float4 v0 = *(const float4*)(src);
    float4 v1 = *(const float4*)(src + 4);
    u32 p0 = pack2(v0.x, v0.y), p1 = pack2(v0.z, v0.w);
    u32 p2 = pack2(v1.x, v1.y), p3 = pack2(v1.z, v1.w);
    int byte = (c * 16) ^ ((h & 7) << 4);
    *(uint4*)((char*)Wz + (size_t)h * 1024 + byte) = make_uint4(p0, p1, p2, p3);
}

// ---------------------------------------------------------------------------
// Prep A: flat[b,f,i] fp32 -> Az bf16, i-major chunk tiles.
// Az chunk (b,kc): 32 KB = [il 0..255][128B row]; within row, 16B unit at
// byte q holds f-elements ((q ^ ((il&7)<<4))/2 + kc*64). This is the exact
// LDS image k_scores DMAs linearly.
__global__ __launch_bounds__(256) void k_prep_a(const float* __restrict__ flat,
                                                u16* __restrict__ Az) {
    __shared__ u16 T[64 * 258];        // [kk][il] natural, stride 258 (bank spread)
    int b = blockIdx.x, kc = blockIdx.y, tid = threadIdx.x;
    const float* src = flat + (size_t)b * (Fn * HWn) + (size_t)kc * 64 * HWn;
    #pragma unroll
    for (int t = 0; t < 16; t++) {
        int idx = t * 256 + tid;
        int kk = idx >> 6;             // 0..63
        int i4 = (idx & 63) * 4;       // 0..252
        float4 v = *(const float4*)(src + kk * HWn + i4);
        u32 lo = pack2(v.x, v.y), hi = pack2(v.z, v.w);
        *(u32*)&T[kk * 258 + i4] = lo;
        *(u32*)&T[kk * 258 + i4 + 2] = hi;
    }
    __syncthreads();
    char* dst = (char*)Az + ((size_t)b * 8 + kc) * 32768;
    #pragma unroll
    for (int j = 0; j < 8; j++) {
        int p = j * 256 + tid;         // 16B unit index
        int il = p >> 3, c = p & 7;
        int kb = ((c * 16) ^ ((il & 7) << 4)) >> 1;   // first kk of this unit
        u32 o[4];
        #pragma unroll
        for (int q = 0; q < 4; q++) {
            u32 v0 = T[(kb + q * 2) * 258 + il];
            u32 v1 = T[(kb + q * 2 + 1) * 258 + il];
            o[q] = (v0 & 0xffffu) | (v1 << 16);
        }
        *(uint4*)(dst + (size_t)p * 16) = make_uint4(o[0], o[1], o[2], o[3]);
    }
}

// ---------------------------------------------------------------------------
// K2 v3: sc[b,i] = (1/51.2) * sum_h tanh(ht[b,h] + sum_f flat[b,f,i]*WFw[h,f])
// One block per b. 8 waves (2i x 4h), wave tile 128i x 64h (R=0.375).
// A (from Az) + W (from Wz) both staged by pure global_load_lds DMA.
// hp: 2 h-passes of 256; kc: 8 K-chunks of 64. A read 2x total (bf16).
__global__ __launch_bounds__(512, 2) void k_scores(
    const u16* __restrict__ Az, const u16* __restrict__ Wz,
    const float* __restrict__ ht, float* __restrict__ sc)
{
    __shared__ u16 Al[256 * 64];   // 32 KB: [il][64kk] swizzled rows
    __shared__ u16 Wl[256 * 64];   // 32 KB: [hl][64kk] swizzled rows
    int b = blockIdx.x, tid = threadIdx.x;
    int w = tid >> 6, lane = tid & 63, lm = lane & 15, quad = lane >> 4;
    int wi = w & 1, wh = w >> 1;
    float part[8][4];
    #pragma unroll
    for (int m = 0; m < 8; m++)
        #pragma unroll
        for (int r = 0; r < 4; r++) part[m][r] = 0.f;

    const char* AzB = (const char*)Az + (size_t)b * (8 * 32768);
    f32x4 zero = {0.f, 0.f, 0.f, 0.f};

    for (int hp = 0; hp < 2; hp++) {
        f32x4 acc[8][4];
        #pragma unroll
        for (int m = 0; m < 8; m++)
            #pragma unroll
            for (int n = 0; n < 4; n++) acc[m][n] = zero;

        for (int kc = 0; kc < 8; kc++) {
            __syncthreads();
            {   // A chunk: 32 KB fully linear
                const char* s = AzB + kc * 32768 + w * 4096 + lane * 16;
                #pragma unroll
                for (int j = 0; j < 4; j++)
                    GLDS16(s + j * 1024, &Al[(w * 32 + j * 8) * 64]);
            }
            {   // W chunk: rows h = hp*256+hl, 128B sub-rows of 1KB Wz rows
                const char* s = (const char*)Wz +
                    (size_t)(hp * 256 + w * 32 + (lane >> 3)) * 1024 +
                    kc * 128 + (lane & 7) * 16;
                #pragma unroll
                for (int j = 0; j < 4; j++)
                    GLDS16(s + j * 8192, &Wl[(w * 32 + j * 8) * 64]);
            }
            __syncthreads();
            #pragma unroll
            for (int ks = 0; ks < 2; ks++) {
                bf16x8 af[8], wf[4];
                #pragma unroll
                for (int m = 0; m < 8; m++) {
                    int row = wi * 128 + m * 16 + lm;
                    af[m] = *(const bf16x8*)&Al[row * 64 +
                        (((ks * 64 + quad * 16) ^ ((row & 7) << 4)) >> 1)];
                }
                #pragma unroll
                for (int n = 0; n < 4; n++) {
                    int row = wh * 64 + n * 16 + lm;
                    wf[n] = *(const bf16x8*)&Wl[row * 64 +
                        (((ks * 64 + quad * 16) ^ ((row & 7) << 4)) >> 1)];
                }
                #pragma unroll
                for (int m = 0; m < 8; m++)
                    #pragma unroll
                    for (int n = 0; n < 4; n++)
                        acc[m][n] = __builtin_amdgcn_mfma_f32_16x16x32_bf16(
                            af[m], wf[n], acc[m][n], 0, 0, 0);
            }
        }
        #pragma unroll
        for (int n = 0; n < 4; n++) {
            float hb = ht[b * Hn + hp * 256 + wh * 64 + n * 16 + lm];
            #pragma unroll
            for (int m = 0; m < 8; m++)
                #pragma unroll
                for (int r = 0; r < 4; r++)
                    part[m][r] += tanh_fast(hb + acc[m][n][r]);
        }
    }
    __syncthreads();
    float* scf = (float*)Al;
    if (tid < 256) scf[tid] = 0.f;
    __syncthreads();
    #pragma unroll
    for (int m = 0; m < 8; m++)
        #pragma unroll
        for (int r = 0; r < 4; r++) {
            float p = part[m][r];
            p += __shfl_xor(p, 1); p += __shfl_xor(p, 2);
            p += __shfl_xor(p, 4); p += __shfl_xor(p, 8);
            if (lm == 0) atomicAdd(&scf[wi * 128 + m * 16 + quad * 4 + r], p);
        }
    __syncthreads();
    if (tid < 256) sc[b * HWn + tid] = scf[tid] * (1.0f / 51.2f);
}

// ---------------------------------------------------------------------------
// K3 v2: softmax over sc; ctx[b,f] = sum_i attn[i]*flat[b,f,i], reading Az
// (bf16, swizzled). Thread -> f pair; coalesced per 128B line (XOR permutes
// within the line). 64 MB total read (was 128 MB fp32).
__global__ void k_attn_ctx(const float* __restrict__ sc, const u16* __restrict__ Az,
                           float* __restrict__ ctx) {
    __shared__ float sa[HWn], r1[HWn];
    int b = blockIdx.x, tid = threadIdx.x;
    float x = sc[b * HWn + tid];
    r1[tid] = x; __syncthreads();
    for (int off = 128; off; off >>= 1) {
        if (tid < off) r1[tid] = fmaxf(r1[tid], r1[tid + off]);
        __syncthreads();
    }
    float M = r1[0];
    __syncthreads();
    float e = __expf(x - M);
    r1[tid] = e; __syncthreads();
    for (int off = 128; off; off >>= 1) {
        if (tid < off) r1[tid] += r1[tid + off];
        __syncthreads();
    }
    sa[tid] = e / r1[0];
    __syncthreads();
    int kc = tid >> 5;
    int sbyte = (tid & 31) * 4;
    const char* base = (const char*)Az + ((size_t)b * 8 + kc) * 32768;
    float a0 = 0.f, a1 = 0.f;
    for (int il0 = 0; il0 < 256; il0 += 8) {
        #pragma unroll
        for (int c = 0; c < 8; c++) {
            int il = il0 + c;
            u32 v = *(const u32*)(base + il * 128 + (sbyte ^ (c << 4)));
            float wv = sa[il];
            a0 += wv * __uint_as_float(v << 16);
            a1 += wv * __uint_as_float(v & 0xffff0000u);
        }
    }
    int f = kc * 64 + (tid & 31) * 2;
    ctx[b * Fn + f]     = a0;
    ctx[b * Fn + f + 1] = a1;
}

// ---------------------------------------------------------------------------
// K6 v2 (logits): out[m,n] = A[m,:512].Wzb[n,:] + bias. N-tile 128 (grid 250),
// 8 waves, wave tile 256m x 16n. W DMA'd once per chunk from prepped bf16
// (read exactly once globally); A (512 KB, L2-resident) VALU-packed per chunk.
__global__ __launch_bounds__(512, 2) void k_gemm2(
    const float* __restrict__ A, const u16* __restrict__ Wzb,
    const float* __restrict__ bias, float* __restrict__ out, int ostride)
{
    __shared__ u16 Al[256 * 64];   // 32 KB swizzled rows
    __shared__ u16 Wl[128 * 64];   // 16 KB swizzled rows
    int tid = threadIdx.x;
    int n0 = blockIdx.x * 128;
    int w = tid >> 6, lane = tid & 63, lm = lane & 15, quad = lane >> 4;
    f32x4 acc[16];
    f32x4 zero = {0.f, 0.f, 0.f, 0.f};
    #pragma unroll
    for (int mi = 0; mi < 16; mi++) acc[mi] = zero;

    for (int kc = 0; kc < 8; kc++) {
        __syncthreads();
        {   // W chunk DMA: 128 rows x 128B
            const char* s = (const char*)Wzb +
                (size_t)(n0 + w * 16 + (lane >> 3)) * 1024 + kc * 128 + (lane & 7) * 16;
            #pragma unroll
            for (int j = 0; j < 2; j++)
                GLDS16(s + j * 8192, &Wl[(w * 16 + j * 8) * 64]);
        }
        // A chunk: 256 rows x 64 k, fp32 -> bf16 pack, swizzled rows
        #pragma unroll
        for (int i = 0; i < 8; i++) {
            int idx = i * 512 + tid;
            int m = idx >> 4;
            int k4 = (idx & 15) * 4;
            float4 v = *(const float4*)(A + (size_t)m * 512 + kc * 64 + k4);
            u32 lo = pack2(v.x, v.y), hi = pack2(v.z, v.w);
            *(uint2*)&Al[m * 64 + (((k4 * 2) ^ ((m & 7) << 4)) >> 1)] = make_uint2(lo, hi);
        }
        __syncthreads();
        #pragma unroll
        for (int ks = 0; ks < 2; ks++) {
            int wrow = w * 16 + lm;
            bf16x8 wf = *(const bf16x8*)&Wl[wrow * 64 +
                (((ks * 64 + quad * 16) ^ ((wrow & 7) << 4)) >> 1)];
            #pragma unroll
            for (int mi = 0; mi < 16; mi++) {
                int row = mi * 16 + lm;
                bf16x8 a = *(const bf16x8*)&Al[row * 64 +
                    (((ks * 64 + quad * 16) ^ ((row & 7) << 4)) >> 1)];
                acc[mi] = __builtin_amdgcn_mfma_f32_16x16x32_bf16(a, wf, acc[mi], 0, 0, 0);
            }
        }
    }
    int n = n0 + w * 16 + lm;
    float bv = bias[n];
    #pragma unroll
    for (int mi = 0; mi < 16; mi++)
        #pragma unroll
        for (int r = 0; r < 4; r++) {
            int m = mi * 16 + quad * 4 + r;
            out[(size_t)m * ostride + n] = acc[mi][r] + bv;
        }
}

// ---------------------------------------------------------------------------
// Fallback copies of round-1 k_scores / k_attn_ctx (used if ws too small).
__device__ __forceinline__ int sxof(int il) {
    return (((il ^ (il >> 3)) & 1) << 2) |
           ((((il >> 1) ^ (il >> 6)) & 1) << 3) |
           (((il >> 4) & 1) << 4) |
           (((il >> 5) & 1) << 5) |
           (((il >> 2) & 1) << 6);
}
__device__ __forceinline__ int aidx(int il, int kk) {
    return il * 128 + (((kk * 2) ^ sxof(il)) >> 1);
}
__global__ __launch_bounds__(256) void k_scores_fb(const float* __restrict__ flat,
                                                   const u16* __restrict__ Wz,
                                                   const float* __restrict__ ht,
                                                   float* __restrict__ sc) {
    __shared__ u16 Al[128 * 128];
    __shared__ u16 Wl[128 * 128];
    int b = blockIdx.x, it = blockIdx.y, tid = threadIdx.x;
    int i0 = it * 128;
    int w = tid >> 6, lane = tid & 63, lm = lane & 15, quad = lane >> 4;
    int wi = w & 1, wh = w >> 1;
    const float* fb = flat + (size_t)b * (Fn * HWn) + i0;
    float part[4][4] = {{0.f}};
    f32x4 zero = {0.f, 0.f, 0.f, 0.f};
    for (int hp = 0; hp < 4; hp++) {
        f32x4 acc[4][4];
        #pragma unroll
        for (int m = 0; m < 4; m++)
            #pragma unroll
            for (int n = 0; n < 4; n++) acc[m][n] = zero;
        for (int kc = 0; kc < 4; kc++) {
            __syncthreads();
            {
                const char* wsrc = (const char*)Wz +
                    (size_t)(hp * 128 + w * 32) * 1024 + kc * 256;
                #pragma unroll
                for (int j = 0; j < 8; j++) {
                    const char* src = wsrc + (size_t)(j * 4 + (lane >> 4)) * 1024
                                    + (lane & 15) * 16;
                    GLDS16(src, &Wl[(w * 32 + j * 4) * 128]);
                }
            }
            #pragma unroll 4
            for (int t = 0; t < 16; t++) {
                int idx = t * 256 + tid;
                int il4 = (idx & 31) * 4;
                int kk = idx >> 5;
                float4 v = *(const float4*)(fb + (size_t)(kc * 128 + kk) * HWn + il4);
                Al[aidx(il4 + 0, kk)] = hi16(v.x);
                Al[aidx(il4 + 1, kk)] = hi16(v.y);
                Al[aidx(il4 + 2, kk)] = hi16(v.z);
                Al[aidx(il4 + 3, kk)] = hi16(v.w);
            }
            __syncthreads();
            #pragma unroll
            for (int ks = 0; ks < 4; ks++) {
                bf16x8 af[4], wf[4];
                #pragma unroll
                for (int m = 0; m < 4; m++) {
                    int il = wi * 64 + m * 16 + lm;
                    union { u32 u[4]; bf16x8 v; } cu;
                    #pragma unroll
                    for (int j = 0; j < 4; j++)
                        cu.u[j] = *(const u32*)&Al[aidx(il, ks * 32 + quad * 8 + 2 * j)];
                    af[m] = cu.v;
                }
                #pragma unroll
                for (int n = 0; n < 4; n++) {
                    int row = wh * 64 + n * 16 + lm;
                    wf[n] = *(const bf16x8*)&Wl[row * 128 +
                             ((ks * 32 + quad * 8) ^ ((row & 7) << 3))];
                }
                #pragma unroll
                for (int m = 0; m < 4; m++)
                    #pragma unroll
                    for (int n = 0; n < 4; n++)
                        acc[m][n] = __builtin_amdgcn_mfma_f32_16x16x32_bf16(
                            af[m], wf[n], acc[m][n], 0, 0, 0);
            }
        }
        #pragma unroll
        for (int n = 0; n < 4; n++) {
            float hb = ht[b * Hn + hp * 128 + wh * 64 + n * 16 + lm];
            #pragma unroll
            for (int m = 0; m < 4; m++)
                #pragma unroll
                for (int r = 0; r < 4; r++)
                    part[m][r] += tanh_fast(hb + acc[m][n][r]);
        }
    }
    __syncthreads();
    float* scf = (float*)Al;
    if (tid < 128) scf[tid] = 0.f;
    __syncthreads();
    #pragma unroll
    for (int m = 0; m < 4; m++)
        #pragma unroll
        for (int r = 0; r < 4; r++) {
            float p = part[m][r];
            p += __shfl_xor(p, 1); p += __shfl_xor(p, 2);
            p += __shfl_xor(p, 4); p += __shfl_xor(p, 8);
            if (lm == 0) atomicAdd(&scf[wi * 64 + m * 16 + quad * 4 + r], p);
        }
    __syncthreads();
    if (tid < 128) sc[b * HWn + i0 + tid] = scf[tid] * (1.0f / 51.2f);
}
__global__ void k_attn_ctx_fb(const float* __restrict__ sc, const float* __restrict__ flat,
                              float* __restrict__ ctx) {
    __shared__ float sa[HWn], r1[HWn];
    int b = blockIdx.x, tid = threadIdx.x;
    float x = sc[b * HWn + tid];
    r1[tid] = x; __syncthreads();
    for (int off = 128; off; off >>= 1) {
        if (tid < off) r1[tid] = fmaxf(r1[tid], r1[tid + off]);
        __syncthreads();
    }
    float M = r1[0];
    __syncthreads();
    float e = __expf(x - M);
    r1[tid] = e; __syncthreads();
    for (int off = 128; off; off >>= 1) {
        if (tid < off) r1[tid] += r1[tid + off];
        __syncthreads();
    }
    sa[tid] = e / r1[0];
    __syncthreads();
    int w = tid >> 6, lane = tid & 63;
    const float4* f4 = (const float4*)(flat + (size_t)b * (Fn * HWn));
    const float4* s4 = (const float4*)sa;
    float4 sv = s4[lane];
    for (int f = w; f < Fn; f += 4) {
        float4 v = f4[f * 64 + lane];
        float acc = v.x * sv.x + v.y * sv.y + v.z * sv.z + v.w * sv.w;
        acc += __shfl_xor(acc, 32); acc += __shfl_xor(acc, 16);
        acc += __shfl_xor(acc, 8);  acc += __shfl_xor(acc, 4);
        acc += __shfl_xor(acc, 2);  acc += __shfl_xor(acc, 1);
        if (lane == 0) ctx[b * Fn + f] = acc;
    }
}

// ---------------------------------------------------------------------------
// K5: LSTM cell elementwise
__global__ void k_lstm(const float* __restrict__ gates, const float* __restrict__ cell,
                       float* __restrict__ oh, float* __restrict__ oc) {
    int idx = blockIdx.x * 256 + threadIdx.x;
    int b = idx >> 9, h = idx & 511;
    const float* g = gates + b * 2048;
    float gi = g[h], gf = g[512 + h], gg = g[1024 + h], go = g[1536 + h];
    float c = cell[idx];
    float cn = sigm(gf) * c + sigm(gi) * tanhf(gg);
    float hv = sigm(go) * tanhf(cn);
    oh[idx] = hv;
    oc[idx] = cn;
}

// ---------------------------------------------------------------------------
// K7: row softmax over V
__global__ void k_vsoftmax(const float* __restrict__ logits, float* __restrict__ probs) {
    __shared__ float rm[256], rs[256];
    int b = blockIdx.x, tid = threadIdx.x;
    const float* row = logits + (size_t)b * Vn;
    float m = -1e30f, s = 0.f;
    for (int v = tid; v < Vn; v += 256) {
        float x = row[v];
        if (x > m) { s = s * __expf(m - x); m = x; }
        s += __expf(x - m);
    }
    rm[tid] = m; rs[tid] = s; __syncthreads();
    for (int off = 128; off; off >>= 1) {
        if (tid < off) {
            float m2 = rm[tid + off], s2 = rs[tid + off];
            float M = fmaxf(rm[tid], m2);
            rs[tid] = rs[tid] * __expf(rm[tid] - M) + s2 * __expf(m2 - M);
            rm[tid] = M;
        }
        __syncthreads();
    }
    float M = rm[0], S = rs[0];
    float* prow = probs + (size_t)b * Vn;
    for (int v = tid; v < Vn; v += 256) prow[v] = __expf(row[v] - M) / S;
}

// ---------------------------------------------------------------------------
extern "C" void kernel_launch(void* const* d_in, const int* in_sizes, int n_in,
                              void* d_out, int out_size, void* d_ws, size_t ws_size,
                              hipStream_t stream) {
    const float* tok    = (const float*)d_in[0];
    const float* hidden = (const float*)d_in[1];
    const float* cell   = (const float*)d_in[2];
    const float* img    = (const float*)d_in[3];
    const float* Whw    = (const float*)d_in[4];
    const float* Whb    = (const float*)d_in[5];
    const float* WFw    = (const float*)d_in[6];
    const float* WFb    = (const float*)d_in[7];
    const float* Wih    = (const float*)d_in[8];
    const float* bih    = (const float*)d_in[9];
    const float* Whh    = (const float*)d_in[10];
    const float* bhh    = (const float*)d_in[11];
    const float* Wow    = (const float*)d_in[12];
    const float* Wob    = (const float*)d_in[13];

    float* out = (float*)d_out;
    float* out_probs  = out;                              // [B*V]
    float* out_h      = out + (size_t)Bn * Vn;            // [B*H]
    float* out_c      = out_h + (size_t)Bn * Hn;          // [B*H]
    float* out_logits = out_c + (size_t)Bn * Hn;          // [B*V]

    float* ws    = (float*)d_ws;
    float* ht    = ws;                // 131072 floats
    float* sc    = ht + 131072;       // 65536
    float* ctx   = sc + 65536;        // 131072
    float* gates = ctx + 131072;      // 524288
    u16*   Wz    = (u16*)(gates + 524288);                // 524288 B
    u16*   Az    = (u16*)((char*)Wz + 524288);            // 67108864 B
    u16*   Wowz  = (u16*)((char*)Az + 67108864);          // 32768000 B
    const size_t NEED = 3407872 + 524288 + 67108864 + 32768000;

    if (ws_size >= NEED) {
        // ---- full path: bf16 prepped A/W, DMA-staged MFMA kernels
        k_prep_a<<<dim3(256, 8), 256, 0, stream>>>(img, Az);
        k_prep_w<<<dim3(128), 256, 0, stream>>>(WFw, Wz);
        k_prep_w<<<dim3(8000), 256, 0, stream>>>(Wow, Wowz);

        // ht = hidden @ Whw^T + Whb + WFb
        k_gemm<<<dim3(4, 16), 512, 0, stream>>>(
            hidden, nullptr, nullptr, Whw, nullptr, nullptr,
            512, 0, 0, 0, 0, 0, 1, Whb, WFb, ht, 512);

        k_scores<<<dim3(256), 512, 0, stream>>>(Az, Wz, ht, sc);
        k_attn_ctx<<<dim3(256), 256, 0, stream>>>(sc, Az, ctx);

        // gates = [tok|ctx] @ Wih^T + hid @ Whh^T + bih + bhh
        k_gemm<<<dim3(4, 64), 512, 0, stream>>>(
            tok, ctx, hidden, Wih, Wih, Whh,
            1024, 1024, 512, 0, 512, 0, 3, bih, bhh, gates, 2048);

        k_lstm<<<dim3(512), 256, 0, stream>>>(gates, cell, out_h, out_c);

        // logits = h_new @ Wow^T + Wob
        k_gemm2<<<dim3(250), 512, 0, stream>>>(out_h, Wowz, Wob, out_logits, Vn);

        k_vsoftmax<<<dim3(256), 256, 0, stream>>>(out_logits, out_probs);
    } else {
        // ---- fallback: round-1 path (needs ~3.9 MB)
        k_prep_w<<<dim3(128), 256, 0, stream>>>(WFw, Wz);
        k_gemm<<<dim3(4, 16), 512, 0, stream>>>(
            hidden, nullptr, nullptr, Whw, nullptr, nullptr,
            512, 0, 0, 0, 0, 0, 1, Whb, WFb, ht, 512);
        k_scores_fb<<<dim3(256, 2), 256, 0, stream>>>(img, Wz, ht, sc);
        k_attn_ctx_fb<<<dim3(256), 256, 0, stream>>>(sc, img, ctx);
        k_gemm<<<dim3(4, 64), 512, 0, stream>>>(
            tok, ctx, hidden, Wih, Wih, Whh,
            1024, 1024, 512, 0, 512, 0, 3, bih, bhh, gates, 2048);
        k_lstm<<<dim3(512), 256, 0, stream>>>(gates, cell, out_h, out_c);
        k_gemm<<<dim3(4, 1000), 512, 0, stream>>>(
            out_h, nullptr, nullptr, Wow, nullptr, nullptr,
            512, 0, 0, 0, 0, 0, 1, Wob, nullptr, out_logits, Vn);
        k_vsoftmax<<<dim3(256), 256, 0, stream>>>(out_logits, out_probs);
    }
}

// Round 3
// 453.754 us; speedup vs baseline: 1.4212x; 1.1305x over previous
//
#include <hip/hip_runtime.h>
#include <stdint.h>

#define Bn  256
#define Hn  512
#define En  512
#define Vn  32000
#define Fn  512
#define HWn 256

typedef unsigned short u16;
typedef unsigned int u32;
typedef __attribute__((ext_vector_type(4))) float f32x4;
typedef __attribute__((ext_vector_type(8))) short bf16x8;

__device__ __forceinline__ u16 hi16(float x) {
    return (u16)((__float_as_uint(x) + 0x8000u) >> 16);
}
__device__ __forceinline__ u32 pack2(float a, float b) {
    return ((__float_as_uint(a) + 0x8000u) >> 16) |
           ((__float_as_uint(b) + 0x8000u) & 0xffff0000u);
}
__device__ __forceinline__ float sigm(float x) { return 1.0f / (1.0f + __expf(-x)); }
__device__ __forceinline__ float tanh_fast(float x) {
    x = fminf(15.f, fmaxf(-15.f, x));
    float e = __expf(2.f * x);
    return 1.f - 2.f / (e + 1.f);
}

#define GLDS16(g, l) __builtin_amdgcn_global_load_lds( \
    (const __attribute__((address_space(1))) void*)(g), \
    (__attribute__((address_space(3))) void*)(l), 16, 0, 0)

// ---------------------------------------------------------------------------
// Generic MFMA GEMM (fp32 inputs, VALU bf16 pack). Used for ht + gates (and
// everything in the fallback path).
__global__ __launch_bounds__(512) void k_gemm(
    const float* __restrict__ A0, const float* __restrict__ A1, const float* __restrict__ A2,
    const float* __restrict__ W0, const float* __restrict__ W1, const float* __restrict__ W2,
    int ws0, int ws1, int ws2, int ko0, int ko1, int ko2, int nseg,
    const float* __restrict__ bias1, const float* __restrict__ bias2,
    float* __restrict__ out, int ostride)
{
    __shared__ u16 Al[64 * 136];
    __shared__ u16 Wl[32 * 136];
    int tid = threadIdx.x;
    int b0 = blockIdx.x * 64, n0 = blockIdx.y * 32;
    int w = tid >> 6, lane = tid & 63, lm = lane & 15, quad = lane >> 4;
    int ti = w & 3, nt = w >> 2;
    const float* As[3] = {A0, A1, A2};
    const float* Ws[3] = {W0, W1, W2};
    int wss[3] = {ws0, ws1, ws2};
    int kos[3] = {ko0, ko1, ko2};
    f32x4 ae = {0.f, 0.f, 0.f, 0.f}, ao = {0.f, 0.f, 0.f, 0.f};
    int ra = ti * 16 + lm, rw = nt * 16 + lm;
    for (int s = 0; s < nseg; s++) {
        const float* Ap = As[s];
        const float* Wp = Ws[s];
        int wstr = wss[s], koff = kos[s];
        for (int kc = 0; kc < 4; kc++) {
            __syncthreads();
            #pragma unroll
            for (int i = 0; i < 4; i++) {
                int idx4 = i * 512 + tid;
                int k4 = (idx4 & 31) * 4;
                int row = idx4 >> 5;
                float4 v = *(const float4*)(Ap + (b0 + row) * 512 + kc * 128 + k4);
                u32 lo = pack2(v.x, v.y), hi = pack2(v.z, v.w);
                *(uint2*)&Al[row * 136 + k4] = make_uint2(lo, hi);
            }
            #pragma unroll
            for (int i = 0; i < 2; i++) {
                int idx4 = i * 512 + tid;
                int k4 = (idx4 & 31) * 4;
                int row = idx4 >> 5;
                float4 v = *(const float4*)(Wp + (size_t)(n0 + row) * wstr + koff + kc * 128 + k4);
                u32 lo = pack2(v.x, v.y), hi = pack2(v.z, v.w);
                *(uint2*)&Wl[row * 136 + k4] = make_uint2(lo, hi);
            }
            __syncthreads();
            #pragma unroll
            for (int ks = 0; ks < 4; ks += 2) {
                bf16x8 a0 = *(const bf16x8*)&Al[ra * 136 + ks * 32 + quad * 8];
                bf16x8 w0 = *(const bf16x8*)&Wl[rw * 136 + ks * 32 + quad * 8];
                ae = __builtin_amdgcn_mfma_f32_16x16x32_bf16(a0, w0, ae, 0, 0, 0);
                bf16x8 a1 = *(const bf16x8*)&Al[ra * 136 + (ks + 1) * 32 + quad * 8];
                bf16x8 w1 = *(const bf16x8*)&Wl[rw * 136 + (ks + 1) * 32 + quad * 8];
                ao = __builtin_amdgcn_mfma_f32_16x16x32_bf16(a1, w1, ao, 0, 0, 0);
            }
        }
    }
    int n = n0 + nt * 16 + lm;
    float bias = bias1[n] + (bias2 ? bias2[n] : 0.f);
    #pragma unroll
    for (int r = 0; r < 4; r++) {
        int m = b0 + ti * 16 + quad * 4 + r;
        out[(size_t)m * ostride + n] = ae[r] + ao[r] + bias;
    }
}

// ---------------------------------------------------------------------------
// Prep: W [rows][512] fp32 -> Wz bf16, rows of 1024 B, pre-swizzled:
// 16B-unit at byte p holds source bytes p ^ ((row&7)<<4). grid = rows/4.
__global__ __launch_bounds__(256) void k_prep_w(const float* __restrict__ W,
                                                u16* __restrict__ Wz) {
    int idx = blockIdx.x * 256 + threadIdx.x;
    int h = idx >> 6, c = idx & 63;
    const float* src = W + (size_t)h * 512 + c * 8;
    float4 v0 = *(const float4*)(src);
    float4 v1 = *(const float4*)(src + 4);
    u32 p0 = pack2(v0.x, v0.y), p1 = pack2(v0.z, v0.w);
    u32 p2 = pack2(v1.x, v1.y), p3 = pack2(v1.z, v1.w);
    int byte = (c * 16) ^ ((h & 7) << 4);
    *(uint4*)((char*)Wz + (size_t)h * 1024 + byte) = make_uint4(p0, p1, p2, p3);
}

// ---------------------------------------------------------------------------
// Prep A: flat[b,f,i] fp32 -> Az bf16, i-major chunk tiles.
// Az chunk (b,kc): 32 KB = [il 0..255][128B row]; within row, 16B unit at
// byte q holds f-elements ((q ^ ((il&7)<<4))/2 + kc*64).
__global__ __launch_bounds__(256) void k_prep_a(const float* __restrict__ flat,
                                                u16* __restrict__ Az) {
    __shared__ u16 T[64 * 258];
    int b = blockIdx.x, kc = blockIdx.y, tid = threadIdx.x;
    const float* src = flat + (size_t)b * (Fn * HWn) + (size_t)kc * 64 * HWn;
    #pragma unroll
    for (int t = 0; t < 16; t++) {
        int idx = t * 256 + tid;
        int kk = idx >> 6;
        int i4 = (idx & 63) * 4;
        float4 v = *(const float4*)(src + kk * HWn + i4);
        u32 lo = pack2(v.x, v.y), hi = pack2(v.z, v.w);
        *(u32*)&T[kk * 258 + i4] = lo;
        *(u32*)&T[kk * 258 + i4 + 2] = hi;
    }
    __syncthreads();
    char* dst = (char*)Az + ((size_t)b * 8 + kc) * 32768;
    #pragma unroll
    for (int j = 0; j < 8; j++) {
        int p = j * 256 + tid;
        int il = p >> 3, c = p & 7;
        int kb = ((c * 16) ^ ((il & 7) << 4)) >> 1;
        u32 o[4];
        #pragma unroll
        for (int q = 0; q < 4; q++) {
            u32 v0 = T[(kb + q * 2) * 258 + il];
            u32 v1 = T[(kb + q * 2 + 1) * 258 + il];
            o[q] = (v0 & 0xffffu) | (v1 << 16);
        }
        *(uint4*)(dst + (size_t)p * 16) = make_uint4(o[0], o[1], o[2], o[3]);
    }
}

// ---------------------------------------------------------------------------
// K2 v3 + fused attention softmax: sc[b,i] = softmax_i of score row.
// One block per b. 8 waves (2i x 4h), wave tile 128i x 64h.
// A (Az) + W (Wz) staged by pure global_load_lds DMA.
__global__ __launch_bounds__(512, 2) void k_scores(
    const u16* __restrict__ Az, const u16* __restrict__ Wz,
    const float* __restrict__ ht, float* __restrict__ sc)
{
    __shared__ u16 Al[256 * 64];
    __shared__ u16 Wl[256 * 64];
    int b = blockIdx.x, tid = threadIdx.x;
    int w = tid >> 6, lane = tid & 63, lm = lane & 15, quad = lane >> 4;
    int wi = w & 1, wh = w >> 1;
    float part[8][4];
    #pragma unroll
    for (int m = 0; m < 8; m++)
        #pragma unroll
        for (int r = 0; r < 4; r++) part[m][r] = 0.f;

    const char* AzB = (const char*)Az + (size_t)b * (8 * 32768);
    f32x4 zero = {0.f, 0.f, 0.f, 0.f};

    for (int hp = 0; hp < 2; hp++) {
        f32x4 acc[8][4];
        #pragma unroll
        for (int m = 0; m < 8; m++)
            #pragma unroll
            for (int n = 0; n < 4; n++) acc[m][n] = zero;

        for (int kc = 0; kc < 8; kc++) {
            __syncthreads();
            {   // A chunk: 32 KB fully linear
                const char* s = AzB + kc * 32768 + w * 4096 + lane * 16;
                #pragma unroll
                for (int j = 0; j < 4; j++)
                    GLDS16(s + j * 1024, &Al[(w * 32 + j * 8) * 64]);
            }
            {   // W chunk
                const char* s = (const char*)Wz +
                    (size_t)(hp * 256 + w * 32 + (lane >> 3)) * 1024 +
                    kc * 128 + (lane & 7) * 16;
                #pragma unroll
                for (int j = 0; j < 4; j++)
                    GLDS16(s + j * 8192, &Wl[(w * 32 + j * 8) * 64]);
            }
            __syncthreads();
            #pragma unroll
            for (int ks = 0; ks < 2; ks++) {
                bf16x8 af[8], wf[4];
                #pragma unroll
                for (int m = 0; m < 8; m++) {
                    int row = wi * 128 + m * 16 + lm;
                    af[m] = *(const bf16x8*)&Al[row * 64 +
                        (((ks * 64 + quad * 16) ^ ((row & 7) << 4)) >> 1)];
                }
                #pragma unroll
                for (int n = 0; n < 4; n++) {
                    int row = wh * 64 + n * 16 + lm;
                    wf[n] = *(const bf16x8*)&Wl[row * 64 +
                        (((ks * 64 + quad * 16) ^ ((row & 7) << 4)) >> 1)];
                }
                #pragma unroll
                for (int m = 0; m < 8; m++)
                    #pragma unroll
                    for (int n = 0; n < 4; n++)
                        acc[m][n] = __builtin_amdgcn_mfma_f32_16x16x32_bf16(
                            af[m], wf[n], acc[m][n], 0, 0, 0);
            }
        }
        #pragma unroll
        for (int n = 0; n < 4; n++) {
            float hb = ht[b * Hn + hp * 256 + wh * 64 + n * 16 + lm];
            #pragma unroll
            for (int m = 0; m < 8; m++)
                #pragma unroll
                for (int r = 0; r < 4; r++)
                    part[m][r] += tanh_fast(hb + acc[m][n][r]);
        }
    }
    __syncthreads();
    float* scf = (float*)Al;           // 256 floats (raw scores)
    float* r1  = (float*)Wl;           // 256 floats (reduce scratch)
    if (tid < 256) scf[tid] = 0.f;
    __syncthreads();
    #pragma unroll
    for (int m = 0; m < 8; m++)
        #pragma unroll
        for (int r = 0; r < 4; r++) {
            float p = part[m][r];
            p += __shfl_xor(p, 1); p += __shfl_xor(p, 2);
            p += __shfl_xor(p, 4); p += __shfl_xor(p, 8);
            if (lm == 0) atomicAdd(&scf[wi * 128 + m * 16 + quad * 4 + r], p);
        }
    __syncthreads();
    // fused softmax over the 256 scores; sc stores normalized attn weights
    float x = 0.f, e = 0.f;
    if (tid < 256) { x = scf[tid] * (1.0f / 51.2f); r1[tid] = x; }
    __syncthreads();
    for (int off = 128; off; off >>= 1) {
        if (tid < off) r1[tid] = fmaxf(r1[tid], r1[tid + off]);
        __syncthreads();
    }
    float M = r1[0];
    __syncthreads();
    if (tid < 256) { e = __expf(x - M); r1[tid] = e; }
    __syncthreads();
    for (int off = 128; off; off >>= 1) {
        if (tid < off) r1[tid] += r1[tid + off];
        __syncthreads();
    }
    if (tid < 256) sc[b * HWn + tid] = e / r1[0];
}

// ---------------------------------------------------------------------------
// K3 v3: sc already holds attn weights; ctx[b,f] = sum_i attn[i]*Az[b,f,i].
__global__ void k_attn_ctx(const float* __restrict__ sc, const u16* __restrict__ Az,
                           float* __restrict__ ctx) {
    __shared__ float sa[HWn];
    int b = blockIdx.x, tid = threadIdx.x;
    sa[tid] = sc[b * HWn + tid];
    __syncthreads();
    int kc = tid >> 5;
    int sbyte = (tid & 31) * 4;
    const char* base = (const char*)Az + ((size_t)b * 8 + kc) * 32768;
    float a0 = 0.f, a1 = 0.f;
    for (int il0 = 0; il0 < 256; il0 += 8) {
        #pragma unroll
        for (int c = 0; c < 8; c++) {
            int il = il0 + c;
            u32 v = *(const u32*)(base + il * 128 + (sbyte ^ (c << 4)));
            float wv = sa[il];
            a0 += wv * __uint_as_float(v << 16);
            a1 += wv * __uint_as_float(v & 0xffff0000u);
        }
    }
    int f = kc * 64 + (tid & 31) * 2;
    ctx[b * Fn + f]     = a0;
    ctx[b * Fn + f + 1] = a1;
}

// ---------------------------------------------------------------------------
// K6 v2 (logits): out[m,n] = A[m,:512].Wzb[n,:] + bias. N-tile 128 (grid 250),
// 8 waves, wave tile 256m x 16n.
__global__ __launch_bounds__(512, 2) void k_gemm2(
    const float* __restrict__ A, const u16* __restrict__ Wzb,
    const float* __restrict__ bias, float* __restrict__ out, int ostride)
{
    __shared__ u16 Al[256 * 64];
    __shared__ u16 Wl[128 * 64];
    int tid = threadIdx.x;
    int n0 = blockIdx.x * 128;
    int w = tid >> 6, lane = tid & 63, lm = lane & 15, quad = lane >> 4;
    f32x4 acc[16];
    f32x4 zero = {0.f, 0.f, 0.f, 0.f};
    #pragma unroll
    for (int mi = 0; mi < 16; mi++) acc[mi] = zero;

    for (int kc = 0; kc < 8; kc++) {
        __syncthreads();
        {
            const char* s = (const char*)Wzb +
                (size_t)(n0 + w * 16 + (lane >> 3)) * 1024 + kc * 128 + (lane & 7) * 16;
            #pragma unroll
            for (int j = 0; j < 2; j++)
                GLDS16(s + j * 8192, &Wl[(w * 16 + j * 8) * 64]);
        }
        #pragma unroll
        for (int i = 0; i < 8; i++) {
            int idx = i * 512 + tid;
            int m = idx >> 4;
            int k4 = (idx & 15) * 4;
            float4 v = *(const float4*)(A + (size_t)m * 512 + kc * 64 + k4);
            u32 lo = pack2(v.x, v.y), hi = pack2(v.z, v.w);
            *(uint2*)&Al[m * 64 + (((k4 * 2) ^ ((m & 7) << 4)) >> 1)] = make_uint2(lo, hi);
        }
        __syncthreads();
        #pragma unroll
        for (int ks = 0; ks < 2; ks++) {
            int wrow = w * 16 + lm;
            bf16x8 wf = *(const bf16x8*)&Wl[wrow * 64 +
                (((ks * 64 + quad * 16) ^ ((wrow & 7) << 4)) >> 1)];
            #pragma unroll
            for (int mi = 0; mi < 16; mi++) {
                int row = mi * 16 + lm;
                bf16x8 a = *(const bf16x8*)&Al[row * 64 +
                    (((ks * 64 + quad * 16) ^ ((row & 7) << 4)) >> 1)];
                acc[mi] = __builtin_amdgcn_mfma_f32_16x16x32_bf16(a, wf, acc[mi], 0, 0, 0);
            }
        }
    }
    int n = n0 + w * 16 + lm;
    float bv = bias[n];
    #pragma unroll
    for (int mi = 0; mi < 16; mi++)
        #pragma unroll
        for (int r = 0; r < 4; r++) {
            int m = mi * 16 + quad * 4 + r;
            out[(size_t)m * ostride + n] = acc[mi][r] + bv;
        }
}

// ---------------------------------------------------------------------------
// Fallback copies of round-1 k_scores / k_attn_ctx (used if ws too small).
__device__ __forceinline__ int sxof(int il) {
    return (((il ^ (il >> 3)) & 1) << 2) |
           ((((il >> 1) ^ (il >> 6)) & 1) << 3) |
           (((il >> 4) & 1) << 4) |
           (((il >> 5) & 1) << 5) |
           (((il >> 2) & 1) << 6);
}
__device__ __forceinline__ int aidx(int il, int kk) {
    return il * 128 + (((kk * 2) ^ sxof(il)) >> 1);
}
__global__ __launch_bounds__(256) void k_scores_fb(const float* __restrict__ flat,
                                                   const u16* __restrict__ Wz,
                                                   const float* __restrict__ ht,
                                                   float* __restrict__ sc) {
    __shared__ u16 Al[128 * 128];
    __shared__ u16 Wl[128 * 128];
    int b = blockIdx.x, it = blockIdx.y, tid = threadIdx.x;
    int i0 = it * 128;
    int w = tid >> 6, lane = tid & 63, lm = lane & 15, quad = lane >> 4;
    int wi = w & 1, wh = w >> 1;
    const float* fb = flat + (size_t)b * (Fn * HWn) + i0;
    float part[4][4] = {{0.f}};
    f32x4 zero = {0.f, 0.f, 0.f, 0.f};
    for (int hp = 0; hp < 4; hp++) {
        f32x4 acc[4][4];
        #pragma unroll
        for (int m = 0; m < 4; m++)
            #pragma unroll
            for (int n = 0; n < 4; n++) acc[m][n] = zero;
        for (int kc = 0; kc < 4; kc++) {
            __syncthreads();
            {
                const char* wsrc = (const char*)Wz +
                    (size_t)(hp * 128 + w * 32) * 1024 + kc * 256;
                #pragma unroll
                for (int j = 0; j < 8; j++) {
                    const char* src = wsrc + (size_t)(j * 4 + (lane >> 4)) * 1024
                                    + (lane & 15) * 16;
                    GLDS16(src, &Wl[(w * 32 + j * 4) * 128]);
                }
            }
            #pragma unroll 4
            for (int t = 0; t < 16; t++) {
                int idx = t * 256 + tid;
                int il4 = (idx & 31) * 4;
                int kk = idx >> 5;
                float4 v = *(const float4*)(fb + (size_t)(kc * 128 + kk) * HWn + il4);
                Al[aidx(il4 + 0, kk)] = hi16(v.x);
                Al[aidx(il4 + 1, kk)] = hi16(v.y);
                Al[aidx(il4 + 2, kk)] = hi16(v.z);
                Al[aidx(il4 + 3, kk)] = hi16(v.w);
            }
            __syncthreads();
            #pragma unroll
            for (int ks = 0; ks < 4; ks++) {
                bf16x8 af[4], wf[4];
                #pragma unroll
                for (int m = 0; m < 4; m++) {
                    int il = wi * 64 + m * 16 + lm;
                    union { u32 u[4]; bf16x8 v; } cu;
                    #pragma unroll
                    for (int j = 0; j < 4; j++)
                        cu.u[j] = *(const u32*)&Al[aidx(il, ks * 32 + quad * 8 + 2 * j)];
                    af[m] = cu.v;
                }
                #pragma unroll
                for (int n = 0; n < 4; n++) {
                    int row = wh * 64 + n * 16 + lm;
                    wf[n] = *(const bf16x8*)&Wl[row * 128 +
                             ((ks * 32 + quad * 8) ^ ((row & 7) << 3))];
                }
                #pragma unroll
                for (int m = 0; m < 4; m++)
                    #pragma unroll
                    for (int n = 0; n < 4; n++)
                        acc[m][n] = __builtin_amdgcn_mfma_f32_16x16x32_bf16(
                            af[m], wf[n], acc[m][n], 0, 0, 0);
            }
        }
        #pragma unroll
        for (int n = 0; n < 4; n++) {
            float hb = ht[b * Hn + hp * 128 + wh * 64 + n * 16 + lm];
            #pragma unroll
            for (int m = 0; m < 4; m++)
                #pragma unroll
                for (int r = 0; r < 4; r++)
                    part[m][r] += tanh_fast(hb + acc[m][n][r]);
        }
    }
    __syncthreads();
    float* scf = (float*)Al;
    if (tid < 128) scf[tid] = 0.f;
    __syncthreads();
    #pragma unroll
    for (int m = 0; m < 4; m++)
        #pragma unroll
        for (int r = 0; r < 4; r++) {
            float p = part[m][r];
            p += __shfl_xor(p, 1); p += __shfl_xor(p, 2);
            p += __shfl_xor(p, 4); p += __shfl_xor(p, 8);
            if (lm == 0) atomicAdd(&scf[wi * 64 + m * 16 + quad * 4 + r], p);
        }
    __syncthreads();
    if (tid < 128) sc[b * HWn + i0 + tid] = scf[tid] * (1.0f / 51.2f);
}
__global__ void k_attn_ctx_fb(const float* __restrict__ sc, const float* __restrict__ flat,
                              float* __restrict__ ctx) {
    __shared__ float sa[HWn], r1[HWn];
    int b = blockIdx.x, tid = threadIdx.x;
    float x = sc[b * HWn + tid];
    r1[tid] = x; __syncthreads();
    for (int off = 128; off; off >>= 1) {
        if (tid < off) r1[tid] = fmaxf(r1[tid], r1[tid + off]);
        __syncthreads();
    }
    float M = r1[0];
    __syncthreads();
    float e = __expf(x - M);
    r1[tid] = e; __syncthreads();
    for (int off = 128; off; off >>= 1) {
        if (tid < off) r1[tid] += r1[tid + off];
        __syncthreads();
    }
    sa[tid] = e / r1[0];
    __syncthreads();
    int w = tid >> 6, lane = tid & 63;
    const float4* f4 = (const float4*)(flat + (size_t)b * (Fn * HWn));
    const float4* s4 = (const float4*)sa;
    float4 sv = s4[lane];
    for (int f = w; f < Fn; f += 4) {
        float4 v = f4[f * 64 + lane];
        float acc = v.x * sv.x + v.y * sv.y + v.z * sv.z + v.w * sv.w;
        acc += __shfl_xor(acc, 32); acc += __shfl_xor(acc, 16);
        acc += __shfl_xor(acc, 8);  acc += __shfl_xor(acc, 4);
        acc += __shfl_xor(acc, 2);  acc += __shfl_xor(acc, 1);
        if (lane == 0) ctx[b * Fn + f] = acc;
    }
}

// ---------------------------------------------------------------------------
// K5: LSTM cell elementwise
__global__ void k_lstm(const float* __restrict__ gates, const float* __restrict__ cell,
                       float* __restrict__ oh, float* __restrict__ oc) {
    int idx = blockIdx.x * 256 + threadIdx.x;
    int b = idx >> 9, h = idx & 511;
    const float* g = gates + b * 2048;
    float gi = g[h], gf = g[512 + h], gg = g[1024 + h], go = g[1536 + h];
    float c = cell[idx];
    float cn = sigm(gf) * c + sigm(gi) * tanhf(gg);
    float hv = sigm(go) * tanhf(cn);
    oh[idx] = hv;
    oc[idx] = cn;
}

// ---------------------------------------------------------------------------
// K7 v2: row softmax over V, register-resident single-read.
// 256 blocks x 512 thr. Each thread holds 16 float4 (strided j*512+tid over
// the row's 8000 float4s; j=15 valid only for tid<320). One read of logits
// (32 MB), one write of probs (32 MB). M/S via wave shfl + tiny LDS.
__global__ __launch_bounds__(512) void k_vsoftmax(const float* __restrict__ logits,
                                                  float* __restrict__ probs) {
    __shared__ float red[16];
    int b = blockIdx.x, tid = threadIdx.x;
    int lane = tid & 63, w = tid >> 6;
    const float4* row = (const float4*)(logits + (size_t)b * Vn);
    float4* prow = (float4*)(probs + (size_t)b * Vn);
    bool tail = (tid < 320);

    float4 v[16];
    float m = -1e30f;
    #pragma unroll
    for (int j = 0; j < 15; j++) {
        v[j] = row[j * 512 + tid];
        m = fmaxf(m, fmaxf(fmaxf(v[j].x, v[j].y), fmaxf(v[j].z, v[j].w)));
    }
    if (tail) {
        v[15] = row[15 * 512 + tid];
        m = fmaxf(m, fmaxf(fmaxf(v[15].x, v[15].y), fmaxf(v[15].z, v[15].w)));
    }
    // wave max
    m = fmaxf(m, __shfl_xor(m, 1));  m = fmaxf(m, __shfl_xor(m, 2));
    m = fmaxf(m, __shfl_xor(m, 4));  m = fmaxf(m, __shfl_xor(m, 8));
    m = fmaxf(m, __shfl_xor(m, 16)); m = fmaxf(m, __shfl_xor(m, 32));
    if (lane == 0) red[w] = m;
    __syncthreads();
    float M = red[0];
    #pragma unroll
    for (int k = 1; k < 8; k++) M = fmaxf(M, red[k]);
    __syncthreads();

    float s = 0.f;
    #pragma unroll
    for (int j = 0; j < 15; j++)
        s += __expf(v[j].x - M) + __expf(v[j].y - M) +
             __expf(v[j].z - M) + __expf(v[j].w - M);
    if (tail)
        s += __expf(v[15].x - M) + __expf(v[15].y - M) +
             __expf(v[15].z - M) + __expf(v[15].w - M);
    s += __shfl_xor(s, 1);  s += __shfl_xor(s, 2);
    s += __shfl_xor(s, 4);  s += __shfl_xor(s, 8);
    s += __shfl_xor(s, 16); s += __shfl_xor(s, 32);
    if (lane == 0) red[8 + w] = s;
    __syncthreads();
    float S = 0.f;
    #pragma unroll
    for (int k = 0; k < 8; k++) S += red[8 + k];
    float inv = 1.0f / S;

    #pragma unroll
    for (int j = 0; j < 15; j++) {
        float4 o;
        o.x = __expf(v[j].x - M) * inv;
        o.y = __expf(v[j].y - M) * inv;
        o.z = __expf(v[j].z - M) * inv;
        o.w = __expf(v[j].w - M) * inv;
        prow[j * 512 + tid] = o;
    }
    if (tail) {
        float4 o;
        o.x = __expf(v[15].x - M) * inv;
        o.y = __expf(v[15].y - M) * inv;
        o.z = __expf(v[15].z - M) * inv;
        o.w = __expf(v[15].w - M) * inv;
        prow[15 * 512 + tid] = o;
    }
}

// ---------------------------------------------------------------------------
extern "C" void kernel_launch(void* const* d_in, const int* in_sizes, int n_in,
                              void* d_out, int out_size, void* d_ws, size_t ws_size,
                              hipStream_t stream) {
    const float* tok    = (const float*)d_in[0];
    const float* hidden = (const float*)d_in[1];
    const float* cell   = (const float*)d_in[2];
    const float* img    = (const float*)d_in[3];
    const float* Whw    = (const float*)d_in[4];
    const float* Whb    = (const float*)d_in[5];
    const float* WFw    = (const float*)d_in[6];
    const float* WFb    = (const float*)d_in[7];
    const float* Wih    = (const float*)d_in[8];
    const float* bih    = (const float*)d_in[9];
    const float* Whh    = (const float*)d_in[10];
    const float* bhh    = (const float*)d_in[11];
    const float* Wow    = (const float*)d_in[12];
    const float* Wob    = (const float*)d_in[13];

    float* out = (float*)d_out;
    float* out_probs  = out;                              // [B*V]
    float* out_h      = out + (size_t)Bn * Vn;            // [B*H]
    float* out_c      = out_h + (size_t)Bn * Hn;          // [B*H]
    float* out_logits = out_c + (size_t)Bn * Hn;          // [B*V]

    float* ws    = (float*)d_ws;
    float* ht    = ws;                // 131072 floats
    float* sc    = ht + 131072;       // 65536
    float* ctx   = sc + 65536;        // 131072
    float* gates = ctx + 131072;      // 524288
    u16*   Wz    = (u16*)(gates + 524288);                // 524288 B
    u16*   Az    = (u16*)((char*)Wz + 524288);            // 67108864 B
    u16*   Wowz  = (u16*)((char*)Az + 67108864);          // 32768000 B
    const size_t NEED = 3407872 + 524288 + 67108864 + 32768000;

    if (ws_size >= NEED) {
        // ---- full path: bf16 prepped A/W, DMA-staged MFMA kernels
        k_prep_a<<<dim3(256, 8), 256, 0, stream>>>(img, Az);
        k_prep_w<<<dim3(128), 256, 0, stream>>>(WFw, Wz);
        k_prep_w<<<dim3(8000), 256, 0, stream>>>(Wow, Wowz);

        // ht = hidden @ Whw^T + Whb + WFb
        k_gemm<<<dim3(4, 16), 512, 0, stream>>>(
            hidden, nullptr, nullptr, Whw, nullptr, nullptr,
            512, 0, 0, 0, 0, 0, 1, Whb, WFb, ht, 512);

        k_scores<<<dim3(256), 512, 0, stream>>>(Az, Wz, ht, sc);   // sc = attn
        k_attn_ctx<<<dim3(256), 256, 0, stream>>>(sc, Az, ctx);

        // gates = [tok|ctx] @ Wih^T + hid @ Whh^T + bih + bhh
        k_gemm<<<dim3(4, 64), 512, 0, stream>>>(
            tok, ctx, hidden, Wih, Wih, Whh,
            1024, 1024, 512, 0, 512, 0, 3, bih, bhh, gates, 2048);

        k_lstm<<<dim3(512), 256, 0, stream>>>(gates, cell, out_h, out_c);

        // logits = h_new @ Wow^T + Wob
        k_gemm2<<<dim3(250), 512, 0, stream>>>(out_h, Wowz, Wob, out_logits, Vn);

        k_vsoftmax<<<dim3(256), 512, 0, stream>>>(out_logits, out_probs);
    } else {
        // ---- fallback: round-1 path (needs ~3.9 MB)
        k_prep_w<<<dim3(128), 256, 0, stream>>>(WFw, Wz);
        k_gemm<<<dim3(4, 16), 512, 0, stream>>>(
            hidden, nullptr, nullptr, Whw, nullptr, nullptr,
            512, 0, 0, 0, 0, 0, 1, Whb, WFb, ht, 512);
        k_scores_fb<<<dim3(256, 2), 256, 0, stream>>>(img, Wz, ht, sc);
        k_attn_ctx_fb<<<dim3(256), 256, 0, stream>>>(sc, img, ctx);
        k_gemm<<<dim3(4, 64), 512, 0, stream>>>(
            tok, ctx, hidden, Wih, Wih, Whh,
            1024, 1024, 512, 0, 512, 0, 3, bih, bhh, gates, 2048);
        k_lstm<<<dim3(512), 256, 0, stream>>>(gates, cell, out_h, out_c);
        k_gemm<<<dim3(4, 1000), 512, 0, stream>>>(
            out_h, nullptr, nullptr, Wow, nullptr, nullptr,
            512, 0, 0, 0, 0, 0, 1, Wob, nullptr, out_logits, Vn);
        k_vsoftmax<<<dim3(256), 512, 0, stream>>>(out_logits, out_probs);
    }
}